// Round 2
// baseline (143.930 us; speedup 1.0000x reference)
//
#include <hip/hip_runtime.h>

// N=512, S=64, C=1024, B=10, PAD=0, NEG=-1e9
#define NN 512
#define SS 64
#define CC 1024
#define BB 10
#define SH2 8              // writer kernel: s-values per block

// ======================= Phase 1: per-n stats =======================
// One block (one wave, 64 threads) per n. Computes the histogram once,
// the global max+sumexp once, and all 64 per-s LSEs. Writes cnt row and
// lse row to workspace; also writes out_v (zeros).
__global__ __launch_bounds__(64) void spop_stats_kernel(
    const int* __restrict__ ban_ids,    // [N,S,B]
    const int* __restrict__ item_ids,   // [N,S]
    float* __restrict__ ws_cnt,         // [N,C]
    float* __restrict__ ws_lse,         // [N,S]
    float* __restrict__ out_v)          // [N,S]
{
    const int n   = blockIdx.x;
    const int tid = threadIdx.x;        // 0..63, exactly one wave

    __shared__ __align__(16) float cnt[CC];

#pragma unroll
    for (int k = 0; k < 4; ++k)
        *reinterpret_cast<float4*>(&cnt[(tid + 64 * k) * 4]) =
            make_float4(0.f, 0.f, 0.f, 0.f);
    __syncthreads();

    // histogram of non-pad items, dropping the LAST non-pad element
    const int id = item_ids[n * SS + tid];
    const bool nonpad = (id != 0);
    const unsigned long long m = __ballot(nonpad);
    const int last = 63 - __clzll(m | 1ull);
    if (nonpad && tid != last) atomicAdd(&cnt[id], 1.0f);
    __syncthreads();

    // each thread owns 16 classes (4x float4); block max then sumexp
    float4 v[4];
#pragma unroll
    for (int k = 0; k < 4; ++k)
        v[k] = *reinterpret_cast<const float4*>(&cnt[(tid + 64 * k) * 4]);

    float mx = v[0].x;
#pragma unroll
    for (int k = 0; k < 4; ++k)
        mx = fmaxf(mx, fmaxf(fmaxf(v[k].x, v[k].y), fmaxf(v[k].z, v[k].w)));
#pragma unroll
    for (int off = 32; off >= 1; off >>= 1)      // butterfly: all lanes get max
        mx = fmaxf(mx, __shfl_xor(mx, off));

    float se = 0.f;
#pragma unroll
    for (int k = 0; k < 4; ++k)
        se += __expf(v[k].x - mx) + __expf(v[k].y - mx) +
              __expf(v[k].z - mx) + __expf(v[k].w - mx);
#pragma unroll
    for (int off = 32; off >= 1; off >>= 1)      // butterfly: all lanes get sum
        se += __shfl_xor(se, off);

    // per-s lse: thread tid handles s = tid (S == 64)
    int ban[BB];
#pragma unroll
    for (int j = 0; j < BB; ++j)
        ban[j] = ban_ids[(n * SS + tid) * BB + j];
    float bsum = 0.f;
#pragma unroll
    for (int j = 0; j < BB; ++j) {
        bool dup = false;
#pragma unroll
        for (int k = 0; k < BB; ++k)
            if (k < j) dup |= (ban[k] == ban[j]);
        if (!dup) bsum += __expf(cnt[ban[j]] - mx);
    }
    const float valid = fmaxf(se - bsum, 1e-30f);
    ws_lse[n * SS + tid] = mx + __logf(valid);
    out_v[n * SS + tid]  = 0.f;

    // persist the cnt row for the writer kernel
#pragma unroll
    for (int k = 0; k < 4; ++k)
        *reinterpret_cast<float4*>(&ws_cnt[(size_t)n * CC + (tid + 64 * k) * 4]) = v[k];
}

// ======================= Phase 2: streaming writer (LDS-free) =======================
// One block = (n, 8 s-values). 256 threads, each owns 4 classes (thread tid
// owns classes 4*tid..4*tid+3). ALL mask/lse inputs are block-uniform, so the
// ban mask is computed with uniform compares instead of an LDS scatter:
// no LDS, no atomics, no __syncthreads — each wave is an independent
// load -> compute -> burst-store stream.
__global__ __launch_bounds__(256) void spop_write_kernel(
    const int* __restrict__ ban_ids,    // [N,S,B]
    const float* __restrict__ ws_cnt,   // [N,C]
    const float* __restrict__ ws_lse,   // [N,S]
    float* __restrict__ out_pi)         // [N,S,C]
{
    const int tid = threadIdx.x;
    const int n   = blockIdx.x >> 3;               // SS/SH2 == 8
    const int s0  = (blockIdx.x & 7) * SH2;
    const int b0  = n * SS + s0;

    // this thread's 4 counts (coalesced, L2-hot: 8 blocks share each row)
    const float4 c4 =
        *reinterpret_cast<const float4*>(&ws_cnt[(size_t)n * CC + tid * 4]);

    // uniform prologue: 8 lse + 80 ban ids, all indexed by block only ->
    // compiler emits scalar loads; mask build is ~3 VALU per ban id.
    float    lse_r[SH2];
    unsigned m4_r[SH2];
#pragma unroll
    for (int s = 0; s < SH2; ++s) {
        lse_r[s] = ws_lse[b0 + s];
        const int* bp = &ban_ids[(size_t)(b0 + s) * BB];
        unsigned m4 = 0u;
#pragma unroll
        for (int j = 0; j < BB; ++j) {
            const int c = bp[j];                   // block-uniform
            if ((c >> 2) == tid) m4 |= 1u << (c & 3);
        }
        m4_r[s] = m4;
    }

    // burst 8 back-to-back float4 stores (4 KB per s-row, fully coalesced)
    float4* obase = reinterpret_cast<float4*>(&out_pi[(size_t)b0 * CC]) + tid;
#pragma unroll
    for (int s = 0; s < SH2; ++s) {
        float4 v = c4;
        if (m4_r[s] & 1u) v.x -= 1e9f;
        if (m4_r[s] & 2u) v.y -= 1e9f;
        if (m4_r[s] & 4u) v.z -= 1e9f;
        if (m4_r[s] & 8u) v.w -= 1e9f;
        const float l = lse_r[s];
        obase[(size_t)s * (CC / 4)] =
            make_float4(v.x - l, v.y - l, v.z - l, v.w - l);
    }
}

extern "C" void kernel_launch(void* const* d_in, const int* in_sizes, int n_in,
                              void* d_out, int out_size, void* d_ws, size_t ws_size,
                              hipStream_t stream) {
    const int* ban_ids  = (const int*)d_in[1];
    const int* item_ids = (const int*)d_in[2];
    float* out_pi = (float*)d_out;                      // [N,S,C]
    float* out_v  = out_pi + (size_t)NN * SS * CC;      // [N,S]

    float* ws_cnt = (float*)d_ws;                       // [N,C]
    float* ws_lse = ws_cnt + (size_t)NN * CC;           // [N,S]

    spop_stats_kernel<<<dim3(NN), dim3(64), 0, stream>>>(
        ban_ids, item_ids, ws_cnt, ws_lse, out_v);
    spop_write_kernel<<<dim3(NN * (SS / SH2)), dim3(256), 0, stream>>>(
        ban_ids, ws_cnt, ws_lse, out_pi);
}